// Round 13
// baseline (189.497 us; speedup 1.0000x reference)
//
#include <hip/hip_runtime.h>

#define SQ2F 0.70710678118654752440f

// Filter taps are compile-time constants (reference _filters() is deterministic;
// float literals round identically to np.float32). Zeros fold out of FMA chains.
static constexpr float H0O[5] = {-0.05f, 0.25f, 0.6f, 0.25f, -0.05f};
static constexpr float H1O[7] = {(float)(-3.0/280.0), (float)(3.0/56.0), (float)(73.0/280.0),
                                 (float)(-17.0/28.0), (float)(73.0/280.0), (float)(3.0/56.0),
                                 (float)(-3.0/280.0)};
static constexpr float H0A[10] = {0.03516384f, 0.0f, -0.08832942f, 0.23389032f, 0.76027237f,
                                  0.5875183f, 0.0f, -0.11430184f, 0.0f, 0.0f};
static constexpr float H0B[10] = {0.0f, 0.0f, -0.11430184f, 0.0f, 0.5875183f,
                                  0.76027237f, 0.23389032f, -0.08832942f, 0.0f, 0.03516384f};
static constexpr float H1A[10] = {0.0f, 0.0f, -0.11430184f, 0.0f, 0.5875183f,
                                  -0.76027237f, 0.23389032f, 0.08832942f, 0.0f, -0.03516384f};
static constexpr float H1B[10] = {-0.03516384f, 0.0f, 0.08832942f, 0.23389032f, -0.76027237f,
                                  0.5875183f, 0.0f, -0.11430184f, 0.0f, 0.0f};

__device__ __forceinline__ int symref(int t, int L) {
    if (t < 0) t = -1 - t;
    if (t >= L) t = 2 * L - 1 - t;
    return t;
}

// async global->LDS, 16 B (dwordx4) per lane — HW-verified (m97). Wave-uniform
// LDS base + lane*16; 16B-aligned global address. Exec-masked lanes drop their
// write (proven by our own passing runs: tail waves 1196 = 2*512+172 were
// partially masked in R5..R7 and results were bit-correct).
__device__ __forceinline__ void gload_lds16(const float* g, float* lds) {
    __builtin_amdgcn_global_load_lds(
        (const __attribute__((address_space(1))) void*)g,
        (__attribute__((address_space(3))) void*)lds, 16, 0, 0);
}

__device__ __forceinline__ float2 f2add(float2 a, float2 b) { return make_float2(a.x + b.x, a.y + b.y); }
__device__ __forceinline__ float2 f2fma(float s, float2 a, float2 b) {
    return make_float2(fmaf(s, a.x, b.x), fmaf(s, a.y, b.y));
}
__device__ __forceinline__ float2 f2s(float s, float2 a) { return make_float2(s * a.x, s * a.y); }

// symmetric 7-tap (H1O) over 7 float2 samples: sum_t H1O[t]*v[6-t]
__device__ __forceinline__ float2 f2sym7(float2 a, float2 b, float2 c, float2 d,
                                         float2 e, float2 f, float2 g) {
    float2 r = f2s(H1O[3], d);
    r = f2fma(H1O[0], f2add(a, g), r);
    r = f2fma(H1O[1], f2add(b, f), r);
    r = f2fma(H1O[2], f2add(c, e), r);
    return r;
}
// symmetric 5-tap (H0O) over 5 float2 samples
__device__ __forceinline__ float2 f2sym5(float2 a, float2 b, float2 c, float2 d, float2 e) {
    float2 r = f2s(H0O[2], c);
    r = f2fma(H0O[0], f2add(a, e), r);
    r = f2fma(H0O[1], f2add(b, d), r);
    return r;
}
// symmetric 5-tap over float4 lanes (4 columns at once)
__device__ __forceinline__ float4 f4sym5(float4 a, float4 b, float4 c, float4 d, float4 e) {
    float4 r;
    r.x = fmaf(H0O[0], a.x + e.x, fmaf(H0O[1], b.x + d.x, H0O[2] * c.x));
    r.y = fmaf(H0O[0], a.y + e.y, fmaf(H0O[1], b.y + d.y, H0O[2] * c.y));
    r.z = fmaf(H0O[0], a.z + e.z, fmaf(H0O[1], b.z + d.z, H0O[2] * c.z));
    r.w = fmaf(H0O[0], a.w + e.w, fmaf(H0O[1], b.w + d.w, H0O[2] * c.w));
    return r;
}

// ---------------------------------------------------------------------------
// Fused levels 1+2. Block = 512 threads; covers x core rows [32ti,32ti+32),
// cols [64tj,64tj+64). Produces yh0 (16x32), yh1 (8x16), ll2 (16x32).
// LDS overlays (46.9 KB -> 3 blocks/CU):
//   S[    0.. 4784) : Xs 52x92 (pitch 92, col base 64tj-12: 16B-aligned DMA)
//                     -> reused as Ls 48x84 after stage 1
//   S[ 4784.. 9152) : Los 52x84 -> after stage 2a, LO2/HI2 48x34 each
//   S[ 9152..11736) : His 38x68
// Pitch 92 = 23 quads (odd): uniform bank-quad histograms for lanes-vary-row
// reads (stage 3). Staging is ONE barrier for every block: interior blocks use
// the flat 1196-unit DMA; column-edge blocks (tj 0/3) DMA the in-bounds span
// per-row-wave and fill reflected edge cols via scalar global loads BEFORE the
// barrier (disjoint LDS ranges; barrier drains vmcnt+lgkmcnt).
// XCD swizzle: bx = ((bx0&7)<<9)|(bx0>>3) — bijective (4096=8*512); all 32
// tiles of an image share bx0%8 -> same XCD L2 -> halo re-reads hit L2.
// The halo IS the symmetric extension (factored symmetric FMA forms make
// reflected windows bit-exact), so stages 2-4 never reflect.
// ---------------------------------------------------------------------------
#define XS(r,c)  S[(r)*92 + (c)]
#define LS(r,c)  S[(r)*84 + (c)]
#define LOS(r,c) S[4784 + (r)*84 + (c)]
#define LO2(r,c) S[4784 + (r)*34 + (c)]
#define HI2(r,c) S[6416 + (r)*34 + (c)]
#define HIS(r,c) S[9152 + (r)*68 + (c)]

__global__ __launch_bounds__(512, 6) void dtcwt_l12(
    const float* __restrict__ x,
    float* __restrict__ yh0,
    float* __restrict__ yh1,
    float* __restrict__ ll2)
{
    __shared__ __align__(16) float S[11736];
    int tid = threadIdx.x;
    int bx0 = blockIdx.x;
    int bx  = ((bx0 & 7) << 9) | (bx0 >> 3);            // XCD-aware, bijective
    int tj = bx & 3, ti = (bx >> 2) & 7, bc = bx >> 5;
    const int xr0 = 32 * ti - 10, xc0 = 64 * tj - 12;   // col base ALIGNED (-12)
    const float* xb = x + (size_t)bc * 65536;
    const int lane = tid & 63;
    const int wv = tid >> 6;                            // 8 waves

    // ---- stage 0: staging, single barrier for ALL blocks.
    if (tj == 1 || tj == 2) {
        // flat 1196-unit 16B DMA (all cols in-bounds: xc0 in {52,116})
        for (int u = tid; u < 1196; u += 512) {
            int r = u / 23, q = u - 23 * r;             // r <= 51
            int rr = symref(xr0 + r, 256);
            gload_lds16(xb + (size_t)rr * 256 + (xc0 + 4 * q), &S[4 * (u - lane)]);
        }
    } else if (tj == 0) {
        // interior tile cols 12..91 = global 0..79 (20 quads/row), per-row wave
        for (int r = wv; r < 52; r += 8) {
            int rr = symref(xr0 + r, 256);
            if (lane < 20)
                gload_lds16(xb + (size_t)rr * 256 + 4 * lane, &S[r * 92 + 12]);
        }
        // edge tile cols 0..11 = global -12..-1 -> reflected source 11-c
        for (int p = tid; p < 624; p += 512) {          // 52 x 12
            int r = p / 12, c = p - 12 * r;
            int rr = symref(xr0 + r, 256);
            S[r * 92 + c] = xb[(size_t)rr * 256 + (11 - c)];
        }
    } else { // tj == 3
        // interior tile cols 0..75 = global 180..255 (19 quads/row)
        for (int r = wv; r < 52; r += 8) {
            int rr = symref(xr0 + r, 256);
            if (lane < 19)
                gload_lds16(xb + (size_t)rr * 256 + 180 + 4 * lane, &S[r * 92]);
        }
        // edge tile cols 76..91 = global 256..271 -> reflected source 331-c
        for (int p = tid; p < 832; p += 512) {          // 52 x 16
            int r = p >> 4, c = 76 + (p & 15);
            int rr = symref(xr0 + r, 256);
            S[r * 92 + c] = xb[(size_t)rr * 256 + (331 - c)];
        }
    }
    __syncthreads();   // drains vmcnt (DMA) + lgkmcnt (scalar ds_writes)

    // ---- stage 1: row filters, 8 outputs/thread, b128 LDS I/O, symmetric taps
    for (int p = tid; p < 520; p += 512) {                  // 52 rows x 10 slots
        int r = p / 10, s = p - r * 10, c8 = 8 * s;
        const float* xr = &XS(r, c8);
        float4 q0 = *(const float4*)&xr[0];
        float4 q1 = *(const float4*)&xr[4];
        float4 q2 = *(const float4*)&xr[8];
        float4 q3 = *(const float4*)&xr[12];
        float u[16] = {q0.x,q0.y,q0.z,q0.w, q1.x,q1.y,q1.z,q1.w,
                       q2.x,q2.y,q2.z,q2.w, q3.x,q3.y,q3.z,q3.w};
        float l[8];
        #pragma unroll
        for (int j = 0; j < 8; j++)
            l[j] = fmaf(H0O[0], u[j+2] + u[j+6],
                   fmaf(H0O[1], u[j+3] + u[j+5], H0O[2] * u[j+4]));
        *(float4*)&LOS(r, c8)     = make_float4(l[0], l[1], l[2], l[3]);
        *(float4*)&LOS(r, c8 + 4) = make_float4(l[4], l[5], l[6], l[7]);
    }
    // hi: window w[j+1..j+7] from 4 quads at c8+8
    for (int p = tid; p < 304; p += 512) {                  // 38 rows x 8 slots
        int r = p >> 3, s = p & 7, c8 = 8 * s;
        const float* xr = &XS(r + 7, c8 + 8);
        float4 q0 = *(const float4*)&xr[0];
        float4 q1 = *(const float4*)&xr[4];
        float4 q2 = *(const float4*)&xr[8];
        float4 q3 = *(const float4*)&xr[12];
        float w[16] = {q0.x,q0.y,q0.z,q0.w, q1.x,q1.y,q1.z,q1.w,
                       q2.x,q2.y,q2.z,q2.w, q3.x,q3.y,q3.z,q3.w};
        float h[8];
        #pragma unroll
        for (int j = 0; j < 8; j++)
            h[j] = fmaf(H1O[0], w[j+1] + w[j+7],
                   fmaf(H1O[1], w[j+2] + w[j+6],
                   fmaf(H1O[2], w[j+3] + w[j+5], H1O[3] * w[j+4])));
        *(float4*)&HIS(r, c8)     = make_float4(h[0], h[1], h[2], h[3]);
        *(float4*)&HIS(r, c8 + 4) = make_float4(h[4], h[5], h[6], h[7]);
    }
    __syncthreads();

    // ---- stage 2b: ll tile, 2 rows x 4 cols per thread, b128 I/O
    for (int p = tid; p < 480; p += 512) {                  // 24 rowpairs x 20 slots
        int rp = p / 20, s = p - rp * 20, c4 = 4 * s;
        const float* l0 = &LOS(2 * rp, c4);
        float4 m0 = *(const float4*)&l0[0];
        float4 m1 = *(const float4*)&l0[84];
        float4 m2 = *(const float4*)&l0[168];
        float4 m3 = *(const float4*)&l0[252];
        float4 m4 = *(const float4*)&l0[336];
        float4 m5 = *(const float4*)&l0[420];
        *(float4*)&LS(2 * rp,     c4) = f4sym5(m0, m1, m2, m3, m4);
        *(float4*)&LS(2 * rp + 1, c4) = f4sym5(m1, m2, m3, m4, m5);
    }
    // ---- stage 2a: yh0, col-pair per thread (b64 reads), in-thread q2c, no shfl
    {
        float* yb = yh0 + (size_t)bc * 196608;
        const size_t bs = 32768;
        int cp = tid & 31, oi = tid >> 5;                   // 32 colpairs x 16 oi
        float2 low[8], hiw[8];
        #pragma unroll
        for (int k = 0; k < 8; k++) {
            low[k] = *(const float2*)&LOS(2 * oi + 7 + k, 2 * cp + 8);
            hiw[k] = *(const float2*)&HIS(2 * oi + k,     2 * cp);
        }
        float2 lhe = f2s(SQ2F, f2sym7(low[0],low[1],low[2],low[3],low[4],low[5],low[6]));
        float2 lho = f2s(SQ2F, f2sym7(low[1],low[2],low[3],low[4],low[5],low[6],low[7]));
        float2 hhe = f2s(SQ2F, f2sym7(hiw[0],hiw[1],hiw[2],hiw[3],hiw[4],hiw[5],hiw[6]));
        float2 hho = f2s(SQ2F, f2sym7(hiw[1],hiw[2],hiw[3],hiw[4],hiw[5],hiw[6],hiw[7]));
        float2 hle = f2s(SQ2F, f2sym5(hiw[1],hiw[2],hiw[3],hiw[4],hiw[5]));
        float2 hlo = f2s(SQ2F, f2sym5(hiw[2],hiw[3],hiw[4],hiw[5],hiw[6]));
        int i0 = 16 * ti + oi, j0 = 32 * tj + cp;
        size_t pix = ((size_t)i0 * 128 + j0) * 2;
        // q2c: a=e.x b=e.y c=o.x d=o.y -> band k (a-d,b+c), band 5-k (a+d,b-c)
        { float a=lhe.x, b=lhe.y, c=lho.x, d=lho.y;
          *(float2*)&yb[0*bs + pix] = make_float2(a-d, b+c);
          *(float2*)&yb[5*bs + pix] = make_float2(a+d, b-c); }
        { float a=hhe.x, b=hhe.y, c=hho.x, d=hho.y;
          *(float2*)&yb[1*bs + pix] = make_float2(a-d, b+c);
          *(float2*)&yb[4*bs + pix] = make_float2(a+d, b-c); }
        { float a=hle.x, b=hle.y, c=hlo.x, d=hlo.y;
          *(float2*)&yb[2*bs + pix] = make_float2(a-d, b+c);
          *(float2*)&yb[3*bs + pix] = make_float2(a+d, b-c); }
    }
    __syncthreads();

    // ---- stage 3: rowdfilt on Ls -> LO2/HI2. b128 window reads; halo in Ls
    // is bit-exactly the symmetric extension, so no reflection path needed.
    for (int p = tid; p < 768; p += 512) {                  // 16 n x 48 rows
        int nl = p / 48, r = p - nl * 48;
        const float* lsr = &LS(r, 4 * nl);
        float4 q0 = *(const float4*)&lsr[0];
        float4 q1 = *(const float4*)&lsr[4];
        float4 q2 = *(const float4*)&lsr[8];
        float4 q3 = *(const float4*)&lsr[12];
        float4 q4 = *(const float4*)&lsr[16];
        float v[20] = {q0.x,q0.y,q0.z,q0.w, q1.x,q1.y,q1.z,q1.w, q2.x,q2.y,q2.z,q2.w,
                       q3.x,q3.y,q3.z,q3.w, q4.x,q4.y,q4.z,q4.w};
        float aLo = 0.f, bLo = 0.f, aHi = 0.f, bHi = 0.f;
        #pragma unroll
        for (int t = 0; t < 10; t++) {
            float vo = v[19 - 2*t], ve = v[18 - 2*t];
            aLo = fmaf(H0B[t], vo, aLo); bLo = fmaf(H0A[t], ve, bLo);
            aHi = fmaf(H1B[t], vo, aHi); bHi = fmaf(H1A[t], ve, bHi);
        }
        *(float2*)&LO2(r, 2*nl) = make_float2(aLo, bLo);   // lowpass : ev=a, od=b
        *(float2*)&HI2(r, 2*nl) = make_float2(bHi, aHi);   // highpass: ev=b, od=a
    }
    __syncthreads();

    // ---- stage 4: coldfilt + q2c -> yh1, ll2. Col-pair per thread (b64),
    // LO2 half (ll+lh) on tid<128, HI2 half (hl+hh) on tid 128..255.
    if (tid < 256) {
        int half = tid >> 7, q = tid & 127;
        int cp = q & 15, li = q >> 4;                       // 16 colpairs x 8 li
        int i1 = 8 * ti + li;
        const float* Bp = half ? &HI2(0, 0) : &LO2(0, 0);
        float2 v[20];
        #pragma unroll
        for (int k = 0; k < 20; k++)
            v[k] = *(const float2*)&Bp[(4 * li + k) * 34 + 2 * cp];
        float2 z = make_float2(0.f, 0.f);
        float2 aA = z, bA = z, aB = z, bB = z;              // A: H0 pair, B: H1 pair
        #pragma unroll
        for (int t = 0; t < 10; t++) {
            float2 vo = v[19 - 2*t], ve = v[18 - 2*t];
            aA = f2fma(H0B[t], vo, aA); bA = f2fma(H0A[t], ve, bA);
            aB = f2fma(H1B[t], vo, aB); bB = f2fma(H1A[t], ve, bB);
        }
        float* yb = yh1 + (size_t)bc * 49152;
        int j1 = 16 * tj + cp;
        size_t pix = ((size_t)i1 * 64 + j1) * 2;
        const size_t bs = 8192;
        if (half == 0) {
            float* llb = ll2 + (size_t)bc * 16384;
            int gc = 32 * tj + 2 * cp;
            *(float2*)&llb[(size_t)(2*i1)     * 128 + gc] = aA;   // ll ev=a
            *(float2*)&llb[(size_t)(2*i1 + 1) * 128 + gc] = bA;   // ll od=b
            float a = SQ2F*bB.x, b = SQ2F*bB.y, c = SQ2F*aB.x, d = SQ2F*aB.y; // lh ev=b,od=a
            *(float2*)&yb[0*bs + pix] = make_float2(a-d, b+c);
            *(float2*)&yb[5*bs + pix] = make_float2(a+d, b-c);
        } else {
            float a = SQ2F*bB.x, b = SQ2F*bB.y, c = SQ2F*aB.x, d = SQ2F*aB.y; // hh ev=b,od=a
            *(float2*)&yb[1*bs + pix] = make_float2(a-d, b+c);
            *(float2*)&yb[4*bs + pix] = make_float2(a+d, b-c);
            a = SQ2F*aA.x; b = SQ2F*aA.y; c = SQ2F*bA.x; d = SQ2F*bA.y;       // hl ev=a,od=b
            *(float2*)&yb[2*bs + pix] = make_float2(a-d, b+c);
            *(float2*)&yb[3*bs + pix] = make_float2(a+d, b-c);
        }
    }
}

// ---------------------------------------------------------------------------
// Level 3: rowdfilt + coldfilt x4 + bands. 512 threads. Single-barrier staging
// (per-row-wave interior DMA + pre-barrier scalar edge loads); same XCD swizzle
// family as l12 so ll2 reads hit the L2 that wrote them.
// ---------------------------------------------------------------------------
#define X2(r,c)  S2[(r)*84 + (c)]
#define LO3(r,c) S2[6720 + (r)*34 + (c)]
#define HI3(r,c) S2[9440 + (r)*34 + (c)]

__global__ __launch_bounds__(512) void level_fused(
    const float* __restrict__ X,
    float* __restrict__ llout,
    float* __restrict__ yh,
    int R, int C, int nbi, int nbj)
{
    __shared__ __align__(16) float S2[12160];

    int tid = threadIdx.x;
    int bx0 = blockIdx.x;
    int bx  = ((bx0 & 7) << 6) | (bx0 >> 3);    // bijective for 512 = 8*64
    int tj = bx % nbj; int ti = (bx / nbj) % nbi; int bc = bx / (nbj * nbi);
    int i0 = ti * 16, j0 = tj * 16;
    int gr0 = 4 * i0 - 8, gc0 = 4 * j0 - 8;     // gc0 % 4 == 0 -> aligned DMA
    const float* Xb = X + (size_t)bc * R * C;
    const int lane = tid & 63;
    const int wv = tid >> 6;

    // stage 0: per-row-wave DMA of in-bounds cols + scalar reflected edges,
    // ONE barrier. cl in {0,8}; cr in {72,84}.
    int cl = (gc0 < 0) ? -gc0 : 0;
    int cr = (gc0 + 84 > C) ? (C - gc0) : 84;
    int nu = (cr - cl) >> 2;                                 // 19 or 18
    for (int r = wv; r < 80; r += 8) {
        int rr = symref(gr0 + r, R);
        if (lane < nu)
            gload_lds16(Xb + (size_t)rr * C + (gc0 + cl) + 4 * lane,
                        &S2[r * 84 + cl]);
    }
    if (cl > 0) {
        for (int p = tid; p < 640; p += 512) {               // 80 x 8
            int r = p >> 3, c = p & 7;
            int rr = symref(gr0 + r, R);
            S2[r * 84 + c] = Xb[(size_t)rr * C + (-1 - gc0 - c)];
        }
    }
    if (cr < 84) {
        for (int p = tid; p < 960; p += 512) {               // 80 x 12
            int r = p / 12, c = cr + (p - r * 12);
            int rr = symref(gr0 + r, R);
            S2[r * 84 + c] = Xb[(size_t)rr * C + (2 * C - 1 - gc0 - c)];
        }
    }
    __syncthreads();

    // rowdfilt: b128 window reads, float2 writes
    for (int p = tid; p < 1280; p += 512) {                  // 16 n x 80 rows
        int nl = p / 80, r = p - nl * 80;
        const float* xr = &X2(r, 4 * nl);
        float4 q0 = *(const float4*)&xr[0];
        float4 q1 = *(const float4*)&xr[4];
        float4 q2 = *(const float4*)&xr[8];
        float4 q3 = *(const float4*)&xr[12];
        float4 q4 = *(const float4*)&xr[16];
        float v[20] = {q0.x,q0.y,q0.z,q0.w, q1.x,q1.y,q1.z,q1.w, q2.x,q2.y,q2.z,q2.w,
                       q3.x,q3.y,q3.z,q3.w, q4.x,q4.y,q4.z,q4.w};
        float aLo = 0.f, bLo = 0.f, aHi = 0.f, bHi = 0.f;
        #pragma unroll
        for (int t = 0; t < 10; t++) {
            float vo = v[19 - 2*t], ve = v[18 - 2*t];
            aLo = fmaf(H0B[t], vo, aLo); bLo = fmaf(H0A[t], ve, bLo);
            aHi = fmaf(H1B[t], vo, aHi); bHi = fmaf(H1A[t], ve, bHi);
        }
        *(float2*)&LO3(r, 2 * nl) = make_float2(aLo, bLo);  // lowpass : ev=a, od=b
        *(float2*)&HI3(r, 2 * nl) = make_float2(bHi, aHi);  // highpass: ev=b, od=a
    }
    __syncthreads();

    // coldfilt + bands: col-pair per thread via b64 reads, in-thread q2c.
    // Half-split (512 threads): tid<256 -> LO3 (ll + band0/5),
    // tid>=256 -> HI3 (bands 1/4 and 2/3).
    {
        int half = tid >> 8, q8 = tid & 255;
        int lj = q8 & 15, li = q8 >> 4;
        int i = i0 + li, j = j0 + lj;
        const float* Bp = half ? &HI3(0, 0) : &LO3(0, 0);
        float2 v[20];
        #pragma unroll
        for (int k = 0; k < 20; k++)
            v[k] = *(const float2*)&Bp[(4 * li + k) * 34 + 2 * lj];
        float2 z = make_float2(0.f, 0.f);
        float2 aA = z, bA = z, aB = z, bB = z;
        #pragma unroll
        for (int t = 0; t < 10; t++) {
            float2 vo = v[19 - 2*t], ve = v[18 - 2*t];
            aA = f2fma(H0B[t], vo, aA); bA = f2fma(H0A[t], ve, bA);
            aB = f2fma(H1B[t], vo, aB); bB = f2fma(H1A[t], ve, bB);
        }
        int R4 = R >> 2, Wq = C >> 2, C2 = C >> 1;
        float* yb = yh + (size_t)bc * 6 * R4 * Wq * 2;
        size_t pix = ((size_t)i * Wq + j) * 2;
        size_t bs  = (size_t)R4 * Wq * 2;
        if (half == 0) {
            float* llb = llout + (size_t)bc * (R >> 1) * C2;
            *(float2*)&llb[(size_t)(2*i)   * C2 + 2*j] = aA;    // ll ev=a
            *(float2*)&llb[(size_t)(2*i+1) * C2 + 2*j] = bA;    // ll od=b
            float a = SQ2F*bB.x, b = SQ2F*bB.y, c = SQ2F*aB.x, d = SQ2F*aB.y; // lh ev=b,od=a
            *(float2*)&yb[0*bs + pix] = make_float2(a-d, b+c);
            *(float2*)&yb[5*bs + pix] = make_float2(a+d, b-c);
        } else {
            float a = SQ2F*bB.x, b = SQ2F*bB.y, c = SQ2F*aB.x, d = SQ2F*aB.y; // hh ev=b,od=a
            *(float2*)&yb[1*bs + pix] = make_float2(a-d, b+c);
            *(float2*)&yb[4*bs + pix] = make_float2(a+d, b-c);
            a = SQ2F*aA.x; b = SQ2F*aA.y; c = SQ2F*bA.x; d = SQ2F*bA.y;       // hl ev=a,od=b
            *(float2*)&yb[2*bs + pix] = make_float2(a-d, b+c);
            *(float2*)&yb[3*bs + pix] = make_float2(a+d, b-c);
        }
    }
}

extern "C" void kernel_launch(void* const* d_in, const int* in_sizes, int n_in,
                              void* d_out, int out_size, void* d_ws, size_t ws_size,
                              hipStream_t stream) {
    const float* x = (const float*)d_in[0];
    float* out = (float*)d_out;

    const int BC = 8 * 16;  // 128

    float* out_ll  = out;                        // 128*64*64
    float* out_yh0 = out + 524288;               // 128*6*128*128*2
    float* out_yh1 = out + 25690112;             // 128*6*64*64*2
    float* out_yh2 = out + 31981568;             // 128*6*32*32*2

    float* ll2 = (float*)d_ws;                   // 128*128*128 floats = 8 MiB

    // fused levels 1+2: x -> yh0, yh1, ll2
    dtcwt_l12<<<BC * 32, 512, 0, stream>>>(x, out_yh0, out_yh1, ll2);

    // level 3: ll2(128x128) -> yh2, final ll(64x64)
    level_fused<<<BC * 4, 512, 0, stream>>>(ll2, out_ll, out_yh2, 128, 128, 2, 2);
}